// Round 6
// baseline (461.411 us; speedup 1.0000x reference)
//
#include <hip/hip_runtime.h>

typedef unsigned short ushort_t;
typedef unsigned int uint_t;
typedef __attribute__((ext_vector_type(8))) short short8;
typedef __attribute__((ext_vector_type(4))) float f32x4;

#define DIM 2048
#define BATCH 8192

// ---------- bf16 helpers (RNE) ----------
__device__ __forceinline__ ushort_t f2bf(float f) {
  union { float f; uint_t u; } x; x.f = f;
  uint_t r = x.u + 0x7fffu + ((x.u >> 16) & 1u);
  return (ushort_t)(r >> 16);
}
__device__ __forceinline__ float bf2f(ushort_t h) {
  union { uint_t u; float f; } x; x.u = ((uint_t)h) << 16; return x.f;
}

// ---------- async global->LDS 16B ----------
__device__ __forceinline__ void gload_lds16(const void* g, void* l) {
  typedef __attribute__((address_space(1))) const unsigned int gu32;
  typedef __attribute__((address_space(3))) unsigned int lu32;
  __builtin_amdgcn_global_load_lds((gu32*)g, (lu32*)l, 16, 0, 0);
}

// ---------- block reduce (256 threads) ----------
__device__ __forceinline__ float block_reduce_sum(float v) {
  #pragma unroll
  for (int off = 32; off; off >>= 1) v += __shfl_down(v, off);
  __shared__ float red[4];
  int t = threadIdx.x;
  if ((t & 63) == 0) red[t >> 6] = v;
  __syncthreads();
  return red[0] + red[1] + red[2] + red[3];
}

// ---------- c = irfft(gate, 2048) ----------
__global__ void k_c(const float* __restrict__ fg, float* __restrict__ c) {
  int n = blockIdx.x;
  int t = threadIdx.x;
  float s = 0.f;
  for (int k = 1 + t; k < 1024; k += 256) {
    int r = (k * n) & 2047;
    float sn, cs;
    sincospif((float)r * (1.0f / 1024.0f), &sn, &cs);
    s += fg[2 * k] * cs - fg[2 * k + 1] * sn;
  }
  float tot = block_reduce_sum(s);
  if (t == 0) {
    float v = fg[0] + ((n & 1) ? -fg[2048] : fg[2048]) + 2.f * tot;
    c[n] = v * (1.0f / 2048.0f);
  }
}

// ---------- b1[n] = sum_m b_in[m] * c[(n-m) mod 2048] ----------
__global__ void k_b1(const float* __restrict__ b_in, const float* __restrict__ c,
                     float* __restrict__ b1) {
  int n = blockIdx.x;
  int t = threadIdx.x;
  float s = 0.f;
  for (int m = t; m < 2048; m += 256) s += b_in[m] * c[(n - m) & 2047];
  float tot = block_reduce_sum(s);
  if (t == 0) b1[n] = tot;
}

// ---------- GT[r][col] = c[(r-col) mod 2048], bf16 ----------
__global__ void k_gt(const float* __restrict__ c, uint_t* __restrict__ gt) {
  int idx = blockIdx.x * 256 + threadIdx.x;
  int r = idx >> 10;
  int c2 = (idx & 1023) << 1;
  uint_t v0 = f2bf(c[(r - c2) & 2047]);
  uint_t v1 = f2bf(c[(r - c2 - 1) & 2047]);
  gt[idx] = v0 | (v1 << 16);
}

// ---------- fp32 -> bf16 cast, 4/thread ----------
__global__ void k_cast4(const float* __restrict__ in, ushort_t* __restrict__ out) {
  long i = (long)blockIdx.x * 256 + threadIdx.x;
  float4 v = ((const float4*)in)[i];
  ushort4 o;
  o.x = f2bf(v.x); o.y = f2bf(v.y); o.z = f2bf(v.z); o.w = f2bf(v.w);
  ((ushort4*)out)[i] = o;
}

// ---------- transpose + cast ----------
__global__ void k_tc(const float* __restrict__ in, ushort_t* __restrict__ out,
                     int R, int C) {
  __shared__ float tile[32][33];
  int bc = blockIdx.x * 32;
  int br = blockIdx.y * 32;
  int tx = threadIdx.x, ty = threadIdx.y;
  #pragma unroll
  for (int i = ty; i < 32; i += 8)
    tile[i][tx] = in[(size_t)(br + i) * C + bc + tx];
  __syncthreads();
  #pragma unroll
  for (int i = ty; i < 32; i += 8)
    out[(size_t)(bc + i) * R + br + tx] = f2bf(tile[tx][i]);
}

// ---------- Wfc1eT[j][m] = bf16(W_fc1[m][j] + W_fc1[m+2048][j]) ----------
__global__ void k_fc1fold(const float* __restrict__ w, ushort_t* __restrict__ out) {
  int idx = blockIdx.x * 256 + threadIdx.x;
  int j = idx >> 11;
  int m = idx & 2047;
  out[idx] = f2bf(w[(size_t)m * 128 + j] + w[(size_t)(m + 2048) * 128 + j]);
}

// ---------- reduce 4 split-K partials (+optional relu) + cast; stride between slices ----------
template <int RELU>
__global__ void k_red4(const float* __restrict__ p, ushort_t* __restrict__ out, int stride) {
  int i = blockIdx.x * 256 + threadIdx.x;
  float s = p[i] + p[i + stride] + p[i + 2 * stride] + p[i + 3 * stride];
  if constexpr (RELU) s = s > 0.f ? s : 0.f;
  out[i] = f2bf(s);
}

// ================= 128^2 MFMA GEMM (m97 structure) =================
// EPI: 0 plain bf16, 1 +bias bf16, 2 relu bf16, 3 sigmoid*aux bf16, 4 +bias f32,
//      5 split-K f32 partial (grid.z = 4 slices)
template <int EPI>
__launch_bounds__(256, 2)
__global__ void gemm_bt(const ushort_t* __restrict__ A, const ushort_t* __restrict__ BT,
                        void* __restrict__ C, const float* __restrict__ bias,
                        const ushort_t* __restrict__ aux, int M, int N, int K) {
  __shared__ ushort_t ldsA[128 * 32];
  __shared__ ushort_t ldsB[128 * 32];
  const int t = threadIdx.x;
  const int wave = t >> 6, lane = t & 63;
  const int bm = blockIdx.x, bn = blockIdx.y;
  const int wr = wave >> 1, wc = wave & 1;
  const int lrow = lane & 15, lk = lane >> 4;

  f32x4 acc[4][4] = {};

  const size_t arow0 = (size_t)bm * 128;
  const size_t brow0 = (size_t)bn * 128;

  int kb = 0, ke = K;
  if constexpr (EPI == 5) { int ks = K >> 2; kb = blockIdx.z * ks; ke = kb + ks; }

  for (int k0 = kb; k0 < ke; k0 += 32) {
    if (k0 != kb) __syncthreads();
    #pragma unroll
    for (int h = 0; h < 2; ++h) {
      int q = t + h * 256;
      int row = q >> 2, slot = q & 3;
      int kc = slot ^ ((row >> 1) & 3);
      const ushort_t* ga = A + (arow0 + row) * K + k0 + kc * 8;
      gload_lds16(ga, &ldsA[(wave * 64 + h * 256) * 8]);
      const ushort_t* gb = BT + (brow0 + row) * K + k0 + kc * 8;
      gload_lds16(gb, &ldsB[(wave * 64 + h * 256) * 8]);
    }
    __syncthreads();

    short8 af[4], bfr[4];
    #pragma unroll
    for (int m = 0; m < 4; ++m) {
      int row = wr * 64 + m * 16 + lrow;
      int slot = lk ^ ((row >> 1) & 3);
      af[m] = *(const short8*)&ldsA[row * 32 + slot * 8];
      int rowb = wc * 64 + m * 16 + lrow;
      int slotb = lk ^ ((rowb >> 1) & 3);
      bfr[m] = *(const short8*)&ldsB[rowb * 32 + slotb * 8];
    }
    #pragma unroll
    for (int m = 0; m < 4; ++m)
      #pragma unroll
      for (int n = 0; n < 4; ++n)
        acc[m][n] = __builtin_amdgcn_mfma_f32_16x16x32_bf16(af[m], bfr[n], acc[m][n], 0, 0, 0);
  }

  const int rbase = bm * 128 + wr * 64;
  const int cbase = bn * 128 + wc * 64;
  #pragma unroll
  for (int m = 0; m < 4; ++m) {
    #pragma unroll
    for (int n = 0; n < 4; ++n) {
      int col = cbase + n * 16 + lrow;
      int row0 = rbase + m * 16 + lk * 4;
      #pragma unroll
      for (int j = 0; j < 4; ++j) {
        int r = row0 + j;
        float v = acc[m][n][j];
        size_t off = (size_t)r * N + col;
        if constexpr (EPI == 0) {
          ((ushort_t*)C)[off] = f2bf(v);
        } else if constexpr (EPI == 1) {
          ((ushort_t*)C)[off] = f2bf(v + bias[col]);
        } else if constexpr (EPI == 2) {
          ((ushort_t*)C)[off] = f2bf(v > 0.f ? v : 0.f);
        } else if constexpr (EPI == 3) {
          float y = 1.f / (1.f + __expf(-v));
          ((ushort_t*)C)[off] = f2bf(bf2f(aux[off]) * y);
        } else if constexpr (EPI == 4) {
          ((float*)C)[off] = v + bias[col];
        } else {
          ((float*)C)[off + (size_t)blockIdx.z * ((size_t)M * N)] = v;
        }
      }
    }
  }
}

// ================= 256^2 8-phase MFMA GEMM, frag-prefetch pipeline =================
// BM=BN=256, BK=64, 512 thr = 8 waves (2M x 4N), per-wave 128x64 out.
// LDS 128KB: buf b at b*65536; A halves +0/+16384; B halves +32768/+49152.
// G4 swizzle: column chunk ^= (row&7)<<4 (involution) on both staging source
// and ds_read. PIPELINE: phase p issues ds_reads for phase p+1's fragments
// into the other register bank, gates MFMA on counted lgkmcnt(N=own issues;
// DS completes in-order) + sched_barrier(0) (rule 18), computes on the bank
// loaded last phase, ONE s_barrier per phase. So the LDS pipe drains UNDER
// the MFMA cluster instead of serializing with it.
// Staging ledger (steady state, iteration covers tiles T,T+1):
//   ph0: A(T+1)->buf1.A [4]     (buf1.A reads done <= ph6-prev, cert ph7-prev)
//   ph1: B(T+2)h0->buf0.B.h0    (buf0.B read ph7-prev, cert ph0)
//   ph2: B(T+2)h1->buf0.B.h1; vmcnt(4)  -> certs A(T+1),B(T+1) for ph3 reads
//   ph3: (no stage; reads buf1 cp0: 8 bfrag + 4 afrag)
//   ph4: A(T+2)h0->buf0.A.h0    (buf0.A reads done <= ph2, cert ph3)
//   ph5: A(T+2)h1->buf0.A.h1
//   ph6: B(T+3)h0->buf1.B.h0; vmcnt(2)  -> certs A(T+2),B(T+2) for ph7 reads
//   ph7: B(T+3)h1->buf1.B.h1   (buf1.B read ph3, cert ph4; reads buf0-next cp0)
// vmcnt never drains to 0 in the loop.
__device__ __forceinline__ void stage_half(const ushort_t* __restrict__ src, size_t gr0,
                                           int k0b, int ksb, char* ldsHalf, int t) {
  #pragma unroll
  for (int l = 0; l < 2; ++l) {
    int p = (l * 512 + t) * 16;                 // physical byte offset in half
    int row = p >> 7;
    int cb = (p & 127) ^ ((row & 7) << 4);      // content column byte (involution)
    const char* g = (const char*)src + (gr0 + row) * (size_t)ksb + k0b + cb;
    char* dst = ldsHalf + (l * 512 + (t & ~63)) * 16;   // wave-uniform base
    gload_lds16(g, dst);
  }
}

__device__ __forceinline__ short8 ldfrag(const char* regionBase, int R, int kk, int lk) {
  int r = R & 127, h = R >> 7;
  int col = (kk * 64 + lk * 16) ^ ((r & 7) << 4);
  return *(const short8*)(regionBase + h * 16384 + r * 128 + col);
}

template <int EPI>   // 0: plain bf16; 1: +bias bf16; 4: +bias f32
__launch_bounds__(512, 2)
__global__ void gemm256(const ushort_t* __restrict__ A, const ushort_t* __restrict__ BT,
                        void* __restrict__ C, const float* __restrict__ bias,
                        int N, int K, int nbn) {
  __shared__ __align__(16) char L[131072];
  const int t = threadIdx.x;
  const int lane = t & 63, wave = t >> 6;
  const int wm = wave >> 2, wn = wave & 3;
  const int lrow = lane & 15, lk = lane >> 4;

  // bijective XCD swizzle (gridDim.x % 8 == 0)
  int d = blockIdx.x;
  int cpx = gridDim.x >> 3;
  int wg = (d & 7) * cpx + (d >> 3);
  const int bm = wg / nbn, bn = wg % nbn;

  const size_t am0 = (size_t)bm * 256;
  const size_t bn0 = (size_t)bn * 256;
  const int ksb = K * 2;
  const int NT = K >> 6;            // K % 128 == 0, NT even

  f32x4 acc[8][4] = {};

  // prologue staging: tile0 A+B -> buf0, tile1 B -> buf1 (12 loads/thread)
  stage_half(A,  am0,       0,   ksb, L + 0,             t);
  stage_half(A,  am0 + 128, 0,   ksb, L + 16384,         t);
  stage_half(BT, bn0,       0,   ksb, L + 32768,         t);
  stage_half(BT, bn0 + 128, 0,   ksb, L + 49152,         t);
  stage_half(BT, bn0,       128, ksb, L + 65536 + 32768, t);
  stage_half(BT, bn0 + 128, 128, ksb, L + 65536 + 49152, t);
  asm volatile("s_waitcnt vmcnt(4)" ::: "memory");   // tile0 landed; B(1) in flight
  __builtin_amdgcn_s_barrier();

  short8 bfr[2][4][2];   // [buffer-bank][n][kk]
  short8 afr[2][2][2];   // [phase-parity bank][mi][kk]

  // prologue prefetch: buf0 cp0 fragments -> banks 0
  #pragma unroll
  for (int n = 0; n < 4; ++n)
    #pragma unroll
    for (int kk = 0; kk < 2; ++kk)
      bfr[0][n][kk] = ldfrag(L + 32768, wn * 64 + n * 16 + lrow, kk, lk);
  #pragma unroll
  for (int mi = 0; mi < 2; ++mi)
    #pragma unroll
    for (int kk = 0; kk < 2; ++kk)
      afr[0][mi][kk] = ldfrag(L + 0, wm * 128 + mi * 16 + lrow, kk, lk);

  for (int T = 0; T < NT; T += 2) {
    int k1 = ((T + 1 < NT) ? T + 1 : NT - 1) * 128;
    int k2 = ((T + 2 < NT) ? T + 2 : NT - 1) * 128;
    int k3 = ((T + 3 < NT) ? T + 3 : NT - 1) * 128;
    #pragma unroll
    for (int ph = 0; ph < 8; ++ph) {
      const int cb = ph >> 2;          // LDS buffer / bfrag bank in use
      const int cp = ph & 3;           // sub-phase within K-tile
      const int cur = ph & 1;          // afrag bank in use

      // ---- prefetch ds_reads for phase ph+1 (other banks) ----
      if (cp == 3) {
        const char* ob = L + (cb ^ 1) * 65536;     // next buffer
        #pragma unroll
        for (int n = 0; n < 4; ++n)
          #pragma unroll
          for (int kk = 0; kk < 2; ++kk)
            bfr[cb ^ 1][n][kk] = ldfrag(ob + 32768, wn * 64 + n * 16 + lrow, kk, lk);
        #pragma unroll
        for (int mi = 0; mi < 2; ++mi)
          #pragma unroll
          for (int kk = 0; kk < 2; ++kk)
            afr[cur ^ 1][mi][kk] = ldfrag(ob, wm * 128 + mi * 16 + lrow, kk, lk);
      } else {
        const char* Ab = L + cb * 65536;
        #pragma unroll
        for (int mi = 0; mi < 2; ++mi)
          #pragma unroll
          for (int kk = 0; kk < 2; ++kk)
            afr[cur ^ 1][mi][kk] =
                ldfrag(Ab, wm * 128 + ((cp + 1) * 2 + mi) * 16 + lrow, kk, lk);
      }

      // ---- staging + counted vmcnt per ledger ----
      if (ph == 0) {
        stage_half(A, am0,       k1, ksb, L + 65536,         t);
        stage_half(A, am0 + 128, k1, ksb, L + 65536 + 16384, t);
      } else if (ph == 1) {
        stage_half(BT, bn0,       k2, ksb, L + 32768, t);
      } else if (ph == 2) {
        stage_half(BT, bn0 + 128, k2, ksb, L + 49152, t);
        asm volatile("s_waitcnt vmcnt(4)" ::: "memory");   // A(T+1),B(T+1) landed
      } else if (ph == 4) {
        stage_half(A, am0,       k2, ksb, L + 0,     t);
      } else if (ph == 5) {
        stage_half(A, am0 + 128, k2, ksb, L + 16384, t);
      } else if (ph == 6) {
        stage_half(BT, bn0,       k3, ksb, L + 65536 + 32768, t);
        asm volatile("s_waitcnt vmcnt(2)" ::: "memory");   // A(T+2),B(T+2) landed
      } else if (ph == 7) {
        stage_half(BT, bn0 + 128, k3, ksb, L + 65536 + 49152, t);
      }

      // ---- gate on LAST phase's reads (DS in-order: <=N outstanding
      //      means everything older is done), fence, compute ----
      if (cp == 3) asm volatile("s_waitcnt lgkmcnt(12)" ::: "memory");
      else         asm volatile("s_waitcnt lgkmcnt(4)" ::: "memory");
      __builtin_amdgcn_sched_barrier(0);
      __builtin_amdgcn_s_setprio(1);
      #pragma unroll
      for (int mi = 0; mi < 2; ++mi)
        #pragma unroll
        for (int n = 0; n < 4; ++n)
          #pragma unroll
          for (int kk = 0; kk < 2; ++kk)
            acc[cp * 2 + mi][n] = __builtin_amdgcn_mfma_f32_16x16x32_bf16(
                afr[cur][mi][kk], bfr[cb][n][kk], acc[cp * 2 + mi][n], 0, 0, 0);
      __builtin_amdgcn_s_setprio(0);
      __builtin_amdgcn_s_barrier();
    }
  }

  const int rbase = bm * 256 + wm * 128;
  const int cbase = bn * 256 + wn * 64;
  #pragma unroll
  for (int mi = 0; mi < 8; ++mi) {
    #pragma unroll
    for (int n = 0; n < 4; ++n) {
      int col = cbase + n * 16 + lrow;
      int row0 = rbase + mi * 16 + lk * 4;
      float bcol = (EPI == 0) ? 0.f : bias[col];
      #pragma unroll
      for (int j = 0; j < 4; ++j) {
        float v = acc[mi][n][j] + bcol;
        size_t off = (size_t)(row0 + j) * N + col;
        if constexpr (EPI == 4) ((float*)C)[off] = v;
        else                    ((ushort_t*)C)[off] = f2bf(v);
      }
    }
  }
}

extern "C" void kernel_launch(void* const* d_in, const int* in_sizes, int n_in,
                              void* d_out, int out_size, void* d_ws, size_t ws_size,
                              hipStream_t stream) {
  const float* x     = (const float*)d_in[0];
  const float* W_in  = (const float*)d_in[1];
  const float* b_in  = (const float*)d_in[2];
  const float* W_out = (const float*)d_in[3];
  const float* b_out = (const float*)d_in[4];
  const float* fg    = (const float*)d_in[5];
  const float* W_fc1 = (const float*)d_in[6];
  const float* W_fc2 = (const float*)d_in[7];

  char* ws = (char*)d_ws;
  float*    c_buf  = (float*)(ws + 0);               // 8 KB
  float*    b1     = (float*)(ws + 8192);            // 8 KB
  ushort_t* WinBf  = (ushort_t*)(ws + 16384);        // 8 MB
  ushort_t* W1T    = (ushort_t*)(ws + 8404992);      // 8 MB
  ushort_t* WoutT  = (ushort_t*)(ws + 16793600);     // 8 MB
  ushort_t* Wfc1eT = (ushort_t*)(ws + 25182208);     // 512 KB
  ushort_t* Wfc2T  = (ushort_t*)(ws + 25706496);     // 512 KB
  float*    foldp  = (float*)(ws + 26230784);        // 64 MB fold split-K partials
                                                     // (dead before x_bf/ht_bf live)
  ushort_t* x_bf   = (ushort_t*)(ws + 26230784);     // 32 MB (dead after ht GEMM)
  float*    fcp    = (float*)(ws + 26230784);        // 16 MB, aliases x_bf
  ushort_t* ht_bf  = (ushort_t*)(ws + 59785216);     // 32 MB
  ushort_t* a_bf   = (ushort_t*)(ws + 93339648);     // 2 MB
  ushort_t* GT     = (ushort_t*)(ws + 95436800);     // 8 MB (dead after fold GEMM)
  ushort_t* g_bf   = (ushort_t*)(ws + 95436800);     // 32 MB, aliases GT
  (void)ws_size; (void)in_sizes; (void)n_in; (void)out_size;

  // prep (weights only; x cast deferred until foldp region is dead)
  k_c<<<2048, 256, 0, stream>>>(fg, c_buf);
  k_b1<<<2048, 256, 0, stream>>>(b_in, c_buf, b1);
  k_gt<<<8192, 256, 0, stream>>>(c_buf, (uint_t*)GT);
  k_cast4<<<4096, 256, 0, stream>>>(W_in, WinBf);

  // W1T = GT @ WinBf^T  [2048 x 2048], split-K x4 -> f32 partials -> bf16
  gemm_bt<5><<<dim3(16, 16, 4), 256, 0, stream>>>(GT, WinBf, foldp, nullptr, nullptr,
                                                  2048, 2048, 2048);
  k_red4<0><<<16384, 256, 0, stream>>>(foldp, W1T, 4194304);

  // remaining prep (foldp now dead)
  k_cast4<<<16384, 256, 0, stream>>>(x, x_bf);
  k_tc<<<dim3(64, 64), dim3(32, 8), 0, stream>>>(W_out, WoutT, 2048, 2048);
  k_tc<<<dim3(64, 4), dim3(32, 8), 0, stream>>>(W_fc2, Wfc2T, 128, 2048);
  k_fc1fold<<<1024, 256, 0, stream>>>(W_fc1, Wfc1eT);

  // ht = x @ W1 + b1     [8192 x 2048] bf16   (256^2 pipelined)
  gemm256<1><<<256, 512, 0, stream>>>(x_bf, W1T, ht_bf, b1, 2048, 2048, 8);
  // fc1 split-K x4: partials = ht @ Wfc1e    [4][8192 x 128] f32
  gemm_bt<5><<<dim3(64, 1, 4), 256, 0, stream>>>(ht_bf, Wfc1eT, fcp, nullptr, nullptr,
                                                 8192, 128, 2048);
  // a = relu(sum partials)                    [8192 x 128] bf16
  k_red4<1><<<4096, 256, 0, stream>>>(fcp, a_bf, 1048576);
  // g = ht * sigmoid(a @ Wfc2)               [8192 x 2048] bf16
  gemm_bt<3><<<dim3(64, 16), 256, 0, stream>>>(a_bf, Wfc2T, g_bf, nullptr, ht_bf,
                                               8192, 2048, 128);
  // out = g @ W_out + b_out                  [8192 x 2048] f32  (256^2 pipelined)
  gemm256<4><<<256, 512, 0, stream>>>(g_bf, WoutT, (float*)d_out, b_out, 2048, 2048, 8);
}

// Round 7
// 387.602 us; speedup vs baseline: 1.1904x; 1.1904x over previous
//
#include <hip/hip_runtime.h>

typedef unsigned short ushort_t;
typedef unsigned int uint_t;
typedef __attribute__((ext_vector_type(8))) short short8;
typedef __attribute__((ext_vector_type(4))) float f32x4;

#define DIM 2048
#define BATCH 8192

// ---------- bf16 helpers (RNE) ----------
__device__ __forceinline__ ushort_t f2bf(float f) {
  union { float f; uint_t u; } x; x.f = f;
  uint_t r = x.u + 0x7fffu + ((x.u >> 16) & 1u);
  return (ushort_t)(r >> 16);
}
__device__ __forceinline__ float bf2f(ushort_t h) {
  union { uint_t u; float f; } x; x.u = ((uint_t)h) << 16; return x.f;
}

// ---------- async global->LDS 16B ----------
__device__ __forceinline__ void gload_lds16(const void* g, void* l) {
  typedef __attribute__((address_space(1))) const unsigned int gu32;
  typedef __attribute__((address_space(3))) unsigned int lu32;
  __builtin_amdgcn_global_load_lds((gu32*)g, (lu32*)l, 16, 0, 0);
}

// ---------- block reduce (256 threads) ----------
__device__ __forceinline__ float block_reduce_sum(float v) {
  #pragma unroll
  for (int off = 32; off; off >>= 1) v += __shfl_down(v, off);
  __shared__ float red[4];
  int t = threadIdx.x;
  if ((t & 63) == 0) red[t >> 6] = v;
  __syncthreads();
  return red[0] + red[1] + red[2] + red[3];
}

// ---------- c = irfft(gate, 2048) ----------
__global__ void k_c(const float* __restrict__ fg, float* __restrict__ c) {
  int n = blockIdx.x;
  int t = threadIdx.x;
  float s = 0.f;
  for (int k = 1 + t; k < 1024; k += 256) {
    int r = (k * n) & 2047;
    float sn, cs;
    sincospif((float)r * (1.0f / 1024.0f), &sn, &cs);
    s += fg[2 * k] * cs - fg[2 * k + 1] * sn;
  }
  float tot = block_reduce_sum(s);
  if (t == 0) {
    float v = fg[0] + ((n & 1) ? -fg[2048] : fg[2048]) + 2.f * tot;
    c[n] = v * (1.0f / 2048.0f);
  }
}

// ---------- b1[n] = sum_m b_in[m] * c[(n-m) mod 2048] ----------
__global__ void k_b1(const float* __restrict__ b_in, const float* __restrict__ c,
                     float* __restrict__ b1) {
  int n = blockIdx.x;
  int t = threadIdx.x;
  float s = 0.f;
  for (int m = t; m < 2048; m += 256) s += b_in[m] * c[(n - m) & 2047];
  float tot = block_reduce_sum(s);
  if (t == 0) b1[n] = tot;
}

// ---------- GT[r][col] = c[(r-col) mod 2048], bf16 ----------
__global__ void k_gt(const float* __restrict__ c, uint_t* __restrict__ gt) {
  int idx = blockIdx.x * 256 + threadIdx.x;
  int r = idx >> 10;
  int c2 = (idx & 1023) << 1;
  uint_t v0 = f2bf(c[(r - c2) & 2047]);
  uint_t v1 = f2bf(c[(r - c2 - 1) & 2047]);
  gt[idx] = v0 | (v1 << 16);
}

// ---------- fp32 -> bf16 cast, 4/thread ----------
__global__ void k_cast4(const float* __restrict__ in, ushort_t* __restrict__ out) {
  long i = (long)blockIdx.x * 256 + threadIdx.x;
  float4 v = ((const float4*)in)[i];
  ushort4 o;
  o.x = f2bf(v.x); o.y = f2bf(v.y); o.z = f2bf(v.z); o.w = f2bf(v.w);
  ((ushort4*)out)[i] = o;
}

// ---------- transpose + cast ----------
__global__ void k_tc(const float* __restrict__ in, ushort_t* __restrict__ out,
                     int R, int C) {
  __shared__ float tile[32][33];
  int bc = blockIdx.x * 32;
  int br = blockIdx.y * 32;
  int tx = threadIdx.x, ty = threadIdx.y;
  #pragma unroll
  for (int i = ty; i < 32; i += 8)
    tile[i][tx] = in[(size_t)(br + i) * C + bc + tx];
  __syncthreads();
  #pragma unroll
  for (int i = ty; i < 32; i += 8)
    out[(size_t)(bc + i) * R + br + tx] = f2bf(tile[tx][i]);
}

// ---------- Wfc1eT[j][m] = bf16(W_fc1[m][j] + W_fc1[m+2048][j]) ----------
__global__ void k_fc1fold(const float* __restrict__ w, ushort_t* __restrict__ out) {
  int idx = blockIdx.x * 256 + threadIdx.x;
  int j = idx >> 11;
  int m = idx & 2047;
  out[idx] = f2bf(w[(size_t)m * 128 + j] + w[(size_t)(m + 2048) * 128 + j]);
}

// ---------- reduce NS split-K partials (+optional relu) + cast ----------
template <int RELU, int NS>
__global__ void k_redN(const float* __restrict__ p, ushort_t* __restrict__ out, int stride) {
  int i = blockIdx.x * 256 + threadIdx.x;
  float s = 0.f;
  #pragma unroll
  for (int j = 0; j < NS; ++j) s += p[i + (size_t)j * stride];
  if constexpr (RELU) s = s > 0.f ? s : 0.f;
  out[i] = f2bf(s);
}

// ================= 128^2 MFMA GEMM (m97 structure) =================
// EPI: 0 plain bf16, 1 +bias bf16, 2 relu bf16, 3 sigmoid*aux bf16, 4 +bias f32,
//      5 split-K x4 f32 partial, 6 split-K x8 f32 partial (grid.z slices)
template <int EPI>
__launch_bounds__(256, 2)
__global__ void gemm_bt(const ushort_t* __restrict__ A, const ushort_t* __restrict__ BT,
                        void* __restrict__ C, const float* __restrict__ bias,
                        const ushort_t* __restrict__ aux, int M, int N, int K) {
  __shared__ ushort_t ldsA[128 * 32];
  __shared__ ushort_t ldsB[128 * 32];
  const int t = threadIdx.x;
  const int wave = t >> 6, lane = t & 63;
  const int bm = blockIdx.x, bn = blockIdx.y;
  const int wr = wave >> 1, wc = wave & 1;
  const int lrow = lane & 15, lk = lane >> 4;

  f32x4 acc[4][4] = {};

  const size_t arow0 = (size_t)bm * 128;
  const size_t brow0 = (size_t)bn * 128;

  int kb = 0, ke = K;
  if constexpr (EPI == 5) { int ks = K >> 2; kb = blockIdx.z * ks; ke = kb + ks; }
  if constexpr (EPI == 6) { int ks = K >> 3; kb = blockIdx.z * ks; ke = kb + ks; }

  for (int k0 = kb; k0 < ke; k0 += 32) {
    if (k0 != kb) __syncthreads();
    #pragma unroll
    for (int h = 0; h < 2; ++h) {
      int q = t + h * 256;
      int row = q >> 2, slot = q & 3;
      int kc = slot ^ ((row >> 1) & 3);
      const ushort_t* ga = A + (arow0 + row) * K + k0 + kc * 8;
      gload_lds16(ga, &ldsA[(wave * 64 + h * 256) * 8]);
      const ushort_t* gb = BT + (brow0 + row) * K + k0 + kc * 8;
      gload_lds16(gb, &ldsB[(wave * 64 + h * 256) * 8]);
    }
    __syncthreads();

    short8 af[4], bfr[4];
    #pragma unroll
    for (int m = 0; m < 4; ++m) {
      int row = wr * 64 + m * 16 + lrow;
      int slot = lk ^ ((row >> 1) & 3);
      af[m] = *(const short8*)&ldsA[row * 32 + slot * 8];
      int rowb = wc * 64 + m * 16 + lrow;
      int slotb = lk ^ ((rowb >> 1) & 3);
      bfr[m] = *(const short8*)&ldsB[rowb * 32 + slotb * 8];
    }
    #pragma unroll
    for (int m = 0; m < 4; ++m)
      #pragma unroll
      for (int n = 0; n < 4; ++n)
        acc[m][n] = __builtin_amdgcn_mfma_f32_16x16x32_bf16(af[m], bfr[n], acc[m][n], 0, 0, 0);
  }

  const int rbase = bm * 128 + wr * 64;
  const int cbase = bn * 128 + wc * 64;
  #pragma unroll
  for (int m = 0; m < 4; ++m) {
    #pragma unroll
    for (int n = 0; n < 4; ++n) {
      int col = cbase + n * 16 + lrow;
      int row0 = rbase + m * 16 + lk * 4;
      #pragma unroll
      for (int j = 0; j < 4; ++j) {
        int r = row0 + j;
        float v = acc[m][n][j];
        size_t off = (size_t)r * N + col;
        if constexpr (EPI == 0) {
          ((ushort_t*)C)[off] = f2bf(v);
        } else if constexpr (EPI == 1) {
          ((ushort_t*)C)[off] = f2bf(v + bias[col]);
        } else if constexpr (EPI == 2) {
          ((ushort_t*)C)[off] = f2bf(v > 0.f ? v : 0.f);
        } else if constexpr (EPI == 3) {
          float y = 1.f / (1.f + __expf(-v));
          ((ushort_t*)C)[off] = f2bf(bf2f(aux[off]) * y);
        } else if constexpr (EPI == 4) {
          ((float*)C)[off] = v + bias[col];
        } else {
          ((float*)C)[off + (size_t)blockIdx.z * ((size_t)M * N)] = v;
        }
      }
    }
  }
}

// ================= 256^2 8-phase MFMA GEMM, ONE barrier per phase =================
// BM=BN=256, BK=64, 512 thr = 8 waves (2M x 4N), per-wave 128x64 out.
// LDS 128KB: buf b at b*65536; A halves +0/+16384; B halves +32768/+49152.
// G4 swizzle: column chunk ^= (row&7)<<4 on staging source and ds_read (R4,
// bank-conflict-free, measured 0). Registers identical to R4 (no prefetch
// banks — R6 showed any extra bank spills: acc 128 AGPR + ~124 VGPR = budget).
//
// ONE-BARRIER phase: [reads for THIS phase | stage | (vmcnt) | s_barrier |
// lgkmcnt(0) | sched_barrier | setprio(1) 16xMFMA setprio(0)] — no 2nd barrier.
// Safety rule (margin-2): a region staged at phase s has last read <= s-2.
// Proof: staging wave passed bar(s-1) => every wave completed its lgkm-gate of
// phase s-2 => all reads of the region completed. Stage slots:
//   ph1: A(T+1) h0+h1 -> buf1.A   (buf1.A last read prev-ph7; margin 2)
//   ph2: B(T+2) h0 -> buf0.B      (buf0.B last read ph0; margin 2)
//   ph3: B(T+2) h1; vmcnt(4)      -> certifies B(T+1)+A(T+1) before ph4 reads
//   ph5: A(T+2) h0 -> buf0.A      (buf0.A last read ph3; margin 2)
//   ph6: A(T+2) h1
//   ph7: B(T+3) h0+h1 -> buf1.B (last read ph4; margin 3); vmcnt(4)
//        -> certifies B(T+2)+A(T+2) before next-ph0 reads
// In-phase read/stage regions are disjoint (checked per slot). vmcnt never
// drains to 0 in the loop; all waits are own-counter (no hang modes).
__device__ __forceinline__ void stage_half(const ushort_t* __restrict__ src, size_t gr0,
                                           int k0b, int ksb, char* ldsHalf, int t) {
  #pragma unroll
  for (int l = 0; l < 2; ++l) {
    int p = (l * 512 + t) * 16;                 // physical byte offset in half
    int row = p >> 7;
    int cb = (p & 127) ^ ((row & 7) << 4);      // content column byte (involution)
    const char* g = (const char*)src + (gr0 + row) * (size_t)ksb + k0b + cb;
    char* dst = ldsHalf + (l * 512 + (t & ~63)) * 16;   // wave-uniform base
    gload_lds16(g, dst);
  }
}

__device__ __forceinline__ short8 ldfrag(const char* regionBase, int R, int kk, int lk) {
  int r = R & 127, h = R >> 7;
  int col = (kk * 64 + lk * 16) ^ ((r & 7) << 4);
  return *(const short8*)(regionBase + h * 16384 + r * 128 + col);
}

template <int EPI>   // 0: plain bf16; 1: +bias bf16; 4: +bias f32
__launch_bounds__(512, 2)
__global__ void gemm256(const ushort_t* __restrict__ A, const ushort_t* __restrict__ BT,
                        void* __restrict__ C, const float* __restrict__ bias,
                        int N, int K, int nbn) {
  __shared__ __align__(16) char L[131072];
  const int t = threadIdx.x;
  const int lane = t & 63, wave = t >> 6;
  const int wm = wave >> 2, wn = wave & 3;
  const int lrow = lane & 15, lk = lane >> 4;

  // bijective XCD swizzle (gridDim.x % 8 == 0)
  int d = blockIdx.x;
  int cpx = gridDim.x >> 3;
  int wg = (d & 7) * cpx + (d >> 3);
  const int bm = wg / nbn, bn = wg % nbn;

  const size_t am0 = (size_t)bm * 256;
  const size_t bn0 = (size_t)bn * 256;
  const int ksb = K * 2;
  const int NT = K >> 6;            // K % 128 == 0, NT even

  f32x4 acc[8][4] = {};

  // prologue: tile0 A+B -> buf0 (8 halves... 4 halves = 8 loads), B(1) -> buf1.B
  stage_half(A,  am0,       0,   ksb, L + 0,             t);
  stage_half(A,  am0 + 128, 0,   ksb, L + 16384,         t);
  stage_half(BT, bn0,       0,   ksb, L + 32768,         t);
  stage_half(BT, bn0 + 128, 0,   ksb, L + 49152,         t);
  stage_half(BT, bn0,       128, ksb, L + 65536 + 32768, t);
  stage_half(BT, bn0 + 128, 128, ksb, L + 65536 + 49152, t);
  asm volatile("s_waitcnt vmcnt(4)" ::: "memory");   // buf0 certified; B(1) in flight
  __builtin_amdgcn_s_barrier();

  short8 bfrag[4][2];
  short8 afrag[2][2];

  for (int T = 0; T < NT; T += 2) {
    int k1 = ((T + 1 < NT) ? T + 1 : NT - 1) * 128;
    int k2 = ((T + 2 < NT) ? T + 2 : NT - 1) * 128;
    int k3 = ((T + 3 < NT) ? T + 3 : NT - 1) * 128;
    #pragma unroll
    for (int ph = 0; ph < 8; ++ph) {
      const int cb = ph >> 2;          // compute buffer
      const int cp = ph & 3;           // sub-phase within K-tile
      const char* Ab = L + cb * 65536;
      const char* Bb = L + cb * 65536 + 32768;

      // ---- reads for THIS phase's MFMA ----
      if (cp == 0) {
        #pragma unroll
        for (int n = 0; n < 4; ++n)
          #pragma unroll
          for (int kk = 0; kk < 2; ++kk)
            bfrag[n][kk] = ldfrag(Bb, wn * 64 + n * 16 + lrow, kk, lk);
      }
      #pragma unroll
      for (int mi = 0; mi < 2; ++mi)
        #pragma unroll
        for (int kk = 0; kk < 2; ++kk)
          afrag[mi][kk] = ldfrag(Ab, wm * 128 + (cp * 2 + mi) * 16 + lrow, kk, lk);

      // ---- staging per margin-2 ledger + counted vmcnt ----
      if (ph == 1) {
        stage_half(A, am0,       k1, ksb, L + 65536,         t);
        stage_half(A, am0 + 128, k1, ksb, L + 65536 + 16384, t);
      } else if (ph == 2) {
        stage_half(BT, bn0,       k2, ksb, L + 32768, t);
      } else if (ph == 3) {
        stage_half(BT, bn0 + 128, k2, ksb, L + 49152, t);
        asm volatile("s_waitcnt vmcnt(4)" ::: "memory");   // A(T+1),B(T+1) landed
      } else if (ph == 5) {
        stage_half(A, am0,       k2, ksb, L + 0,     t);
      } else if (ph == 6) {
        stage_half(A, am0 + 128, k2, ksb, L + 16384, t);
      } else if (ph == 7) {
        stage_half(BT, bn0,       k3, ksb, L + 65536 + 32768, t);
        stage_half(BT, bn0 + 128, k3, ksb, L + 65536 + 49152, t);
        asm volatile("s_waitcnt vmcnt(4)" ::: "memory");   // A(T+2),B(T+2) landed
      }

      __builtin_amdgcn_s_barrier();
      asm volatile("s_waitcnt lgkmcnt(0)" ::: "memory");
      __builtin_amdgcn_sched_barrier(0);
      __builtin_amdgcn_s_setprio(1);
      #pragma unroll
      for (int mi = 0; mi < 2; ++mi)
        #pragma unroll
        for (int n = 0; n < 4; ++n)
          #pragma unroll
          for (int kk = 0; kk < 2; ++kk)
            acc[cp * 2 + mi][n] = __builtin_amdgcn_mfma_f32_16x16x32_bf16(
                afrag[mi][kk], bfrag[n][kk], acc[cp * 2 + mi][n], 0, 0, 0);
      __builtin_amdgcn_s_setprio(0);
      // no second barrier: margin-2 ledger makes it unnecessary
    }
  }

  const int rbase = bm * 256 + wm * 128;
  const int cbase = bn * 256 + wn * 64;
  #pragma unroll
  for (int mi = 0; mi < 8; ++mi) {
    #pragma unroll
    for (int n = 0; n < 4; ++n) {
      int col = cbase + n * 16 + lrow;
      int row0 = rbase + mi * 16 + lk * 4;
      float bcol = (EPI == 0) ? 0.f : bias[col];
      #pragma unroll
      for (int j = 0; j < 4; ++j) {
        float v = acc[mi][n][j] + bcol;
        size_t off = (size_t)(row0 + j) * N + col;
        if constexpr (EPI == 4) ((float*)C)[off] = v;
        else                    ((ushort_t*)C)[off] = f2bf(v);
      }
    }
  }
}

extern "C" void kernel_launch(void* const* d_in, const int* in_sizes, int n_in,
                              void* d_out, int out_size, void* d_ws, size_t ws_size,
                              hipStream_t stream) {
  const float* x     = (const float*)d_in[0];
  const float* W_in  = (const float*)d_in[1];
  const float* b_in  = (const float*)d_in[2];
  const float* W_out = (const float*)d_in[3];
  const float* b_out = (const float*)d_in[4];
  const float* fg    = (const float*)d_in[5];
  const float* W_fc1 = (const float*)d_in[6];
  const float* W_fc2 = (const float*)d_in[7];

  char* ws = (char*)d_ws;
  float*    c_buf  = (float*)(ws + 0);               // 8 KB
  float*    b1     = (float*)(ws + 8192);            // 8 KB
  ushort_t* WinBf  = (ushort_t*)(ws + 16384);        // 8 MB
  ushort_t* W1T    = (ushort_t*)(ws + 8404992);      // 8 MB
  ushort_t* WoutT  = (ushort_t*)(ws + 16793600);     // 8 MB
  ushort_t* Wfc1eT = (ushort_t*)(ws + 25182208);     // 512 KB
  ushort_t* Wfc2T  = (ushort_t*)(ws + 25706496);     // 512 KB
  float*    foldp  = (float*)(ws + 26230784);        // 64 MB fold split-K partials
  ushort_t* x_bf   = (ushort_t*)(ws + 26230784);     // 32 MB (dead after ht GEMM)
  float*    fcp    = (float*)(ws + 26230784);        // 32 MB, aliases x_bf
  ushort_t* ht_bf  = (ushort_t*)(ws + 59785216);     // 32 MB
  ushort_t* a_bf   = (ushort_t*)(ws + 93339648);     // 2 MB
  ushort_t* GT     = (ushort_t*)(ws + 95436800);     // 8 MB (dead after fold GEMM)
  ushort_t* g_bf   = (ushort_t*)(ws + 95436800);     // 32 MB, aliases GT
  (void)ws_size; (void)in_sizes; (void)n_in; (void)out_size;

  // prep (weights only; x cast deferred until foldp region is dead)
  k_c<<<2048, 256, 0, stream>>>(fg, c_buf);
  k_b1<<<2048, 256, 0, stream>>>(b_in, c_buf, b1);
  k_gt<<<8192, 256, 0, stream>>>(c_buf, (uint_t*)GT);
  k_cast4<<<4096, 256, 0, stream>>>(W_in, WinBf);

  // W1T = GT @ WinBf^T  [2048 x 2048], split-K x4 -> f32 partials -> bf16
  gemm_bt<5><<<dim3(16, 16, 4), 256, 0, stream>>>(GT, WinBf, foldp, nullptr, nullptr,
                                                  2048, 2048, 2048);
  k_redN<0, 4><<<16384, 256, 0, stream>>>(foldp, W1T, 4194304);

  // remaining prep (foldp now dead)
  k_cast4<<<16384, 256, 0, stream>>>(x, x_bf);
  k_tc<<<dim3(64, 64), dim3(32, 8), 0, stream>>>(W_out, WoutT, 2048, 2048);
  k_tc<<<dim3(64, 4), dim3(32, 8), 0, stream>>>(W_fc2, Wfc2T, 128, 2048);
  k_fc1fold<<<1024, 256, 0, stream>>>(W_fc1, Wfc1eT);

  // ht = x @ W1 + b1     [8192 x 2048] bf16   (256^2 one-barrier 8-phase)
  gemm256<1><<<256, 512, 0, stream>>>(x_bf, W1T, ht_bf, b1, 2048, 2048, 8);
  // fc1 split-K x8: partials = ht @ Wfc1e    [8][8192 x 128] f32
  gemm_bt<6><<<dim3(64, 1, 8), 256, 0, stream>>>(ht_bf, Wfc1eT, fcp, nullptr, nullptr,
                                                 8192, 128, 2048);
  // a = relu(sum partials)                    [8192 x 128] bf16
  k_redN<1, 8><<<4096, 256, 0, stream>>>(fcp, a_bf, 1048576);
  // g = ht * sigmoid(a @ Wfc2)               [8192 x 2048] bf16
  gemm_bt<3><<<dim3(64, 16), 256, 0, stream>>>(a_bf, Wfc2T, g_bf, nullptr, ht_bf,
                                               8192, 2048, 128);
  // out = g @ W_out + b_out                  [8192 x 2048] f32  (256^2 one-barrier)
  gemm256<4><<<256, 512, 0, stream>>>(g_bf, WoutT, (float*)d_out, b_out, 2048, 2048, 8);
}

// Round 8
// 362.196 us; speedup vs baseline: 1.2739x; 1.0701x over previous
//
#include <hip/hip_runtime.h>

typedef unsigned short ushort_t;
typedef unsigned int uint_t;
typedef __attribute__((ext_vector_type(8))) short short8;
typedef __attribute__((ext_vector_type(4))) float f32x4;

#define DIM 2048
#define BATCH 8192

// ---------- bf16 helpers (RNE) ----------
__device__ __forceinline__ ushort_t f2bf(float f) {
  union { float f; uint_t u; } x; x.f = f;
  uint_t r = x.u + 0x7fffu + ((x.u >> 16) & 1u);
  return (ushort_t)(r >> 16);
}
__device__ __forceinline__ float bf2f(ushort_t h) {
  union { uint_t u; float f; } x; x.u = ((uint_t)h) << 16; return x.f;
}

// ---------- async global->LDS 16B ----------
__device__ __forceinline__ void gload_lds16(const void* g, void* l) {
  typedef __attribute__((address_space(1))) const unsigned int gu32;
  typedef __attribute__((address_space(3))) unsigned int lu32;
  __builtin_amdgcn_global_load_lds((gu32*)g, (lu32*)l, 16, 0, 0);
}

// ---------- block reduce (256 threads) ----------
__device__ __forceinline__ float block_reduce_sum(float v) {
  #pragma unroll
  for (int off = 32; off; off >>= 1) v += __shfl_down(v, off);
  __shared__ float red[4];
  int t = threadIdx.x;
  if ((t & 63) == 0) red[t >> 6] = v;
  __syncthreads();
  return red[0] + red[1] + red[2] + red[3];
}

// ================= fused weight/x prep (block-range partitioned) =================
// parts (block-uniform branch; __syncthreads only inside transpose parts):
//  [0,2048)        k_c: c = irfft(gate, 2048)
//  [2048,6144)     W_in cast -> WinBf (4/thread)
//  [6144,22528)    x cast -> x_bf (4/thread)
//  [22528,26624)   W_out transpose+cast -> WoutT (2048x2048)
//  [26624,26880)   W_fc2 transpose+cast -> Wfc2T (128x2048)
//  [26880,27904)   fc1 fold: Wfc1eT[j][m] = bf16(Wfc1[m][j]+Wfc1[m+2048][j])
__global__ void k_prep_w(const float* __restrict__ fg, float* __restrict__ c,
                         const float* __restrict__ W_in, ushort_t* __restrict__ WinBf,
                         const float* __restrict__ x, ushort_t* __restrict__ x_bf,
                         const float* __restrict__ W_out, ushort_t* __restrict__ WoutT,
                         const float* __restrict__ W_fc2, ushort_t* __restrict__ Wfc2T,
                         const float* __restrict__ W_fc1, ushort_t* __restrict__ Wfc1eT) {
  __shared__ float tile[32][33];
  const int b = blockIdx.x;
  const int t = threadIdx.x;
  if (b < 2048) {
    int n = b;
    float s = 0.f;
    for (int k = 1 + t; k < 1024; k += 256) {
      int r = (k * n) & 2047;
      float sn, cs;
      sincospif((float)r * (1.0f / 1024.0f), &sn, &cs);
      s += fg[2 * k] * cs - fg[2 * k + 1] * sn;
    }
    float tot = block_reduce_sum(s);
    if (t == 0) {
      float v = fg[0] + ((n & 1) ? -fg[2048] : fg[2048]) + 2.f * tot;
      c[n] = v * (1.0f / 2048.0f);
    }
  } else if (b < 6144) {
    long i = (long)(b - 2048) * 256 + t;
    float4 v = ((const float4*)W_in)[i];
    ushort4 o; o.x = f2bf(v.x); o.y = f2bf(v.y); o.z = f2bf(v.z); o.w = f2bf(v.w);
    ((ushort4*)WinBf)[i] = o;
  } else if (b < 22528) {
    long i = (long)(b - 6144) * 256 + t;
    float4 v = ((const float4*)x)[i];
    ushort4 o; o.x = f2bf(v.x); o.y = f2bf(v.y); o.z = f2bf(v.z); o.w = f2bf(v.w);
    ((ushort4*)x_bf)[i] = o;
  } else if (b < 26624) {
    int i2 = b - 22528;                 // 64x64 tiles, R=C=2048
    int bc = (i2 & 63) * 32, br = (i2 >> 6) * 32;
    int tx = t & 31, ty = t >> 5;
    #pragma unroll
    for (int i = ty; i < 32; i += 8)
      tile[i][tx] = W_out[(size_t)(br + i) * 2048 + bc + tx];
    __syncthreads();
    #pragma unroll
    for (int i = ty; i < 32; i += 8)
      WoutT[(size_t)(bc + i) * 2048 + br + tx] = f2bf(tile[tx][i]);
  } else if (b < 26880) {
    int i2 = b - 26624;                 // 64x4 tiles, R=128, C=2048
    int bc = (i2 & 63) * 32, br = (i2 >> 6) * 32;
    int tx = t & 31, ty = t >> 5;
    #pragma unroll
    for (int i = ty; i < 32; i += 8)
      tile[i][tx] = W_fc2[(size_t)(br + i) * 2048 + bc + tx];
    __syncthreads();
    #pragma unroll
    for (int i = ty; i < 32; i += 8)
      Wfc2T[(size_t)(bc + i) * 128 + br + tx] = f2bf(tile[tx][i]);
  } else {
    int idx = (b - 26880) * 256 + t;    // 128*2048
    int j = idx >> 11, m = idx & 2047;
    Wfc1eT[idx] = f2bf(W_fc1[(size_t)m * 128 + j] + W_fc1[(size_t)(m + 2048) * 128 + j]);
  }
}

// ================= fused c-dependent prep: b1 + GT =================
//  [0,2048)      b1[n] = sum_m b_in[m] * c[(n-m) mod 2048]
//  [2048,10240)  GT[r][col] = c[(r-col) mod 2048], bf16 packed
__global__ void k_prep_c(const float* __restrict__ b_in, const float* __restrict__ c,
                         float* __restrict__ b1, uint_t* __restrict__ gt) {
  const int b = blockIdx.x;
  const int t = threadIdx.x;
  if (b < 2048) {
    int n = b;
    float s = 0.f;
    for (int m = t; m < 2048; m += 256) s += b_in[m] * c[(n - m) & 2047];
    float tot = block_reduce_sum(s);
    if (t == 0) b1[n] = tot;
  } else {
    int idx = (b - 2048) * 256 + t;
    int r = idx >> 10;
    int c2 = (idx & 1023) << 1;
    uint_t v0 = f2bf(c[(r - c2) & 2047]);
    uint_t v1 = f2bf(c[(r - c2 - 1) & 2047]);
    gt[idx] = v0 | (v1 << 16);
  }
}

// ---------- reduce NS split-K partials (+optional relu) + cast ----------
template <int RELU, int NS>
__global__ void k_redN(const float* __restrict__ p, ushort_t* __restrict__ out, int stride) {
  int i = blockIdx.x * 256 + threadIdx.x;
  float s = 0.f;
  #pragma unroll
  for (int j = 0; j < NS; ++j) s += p[i + (size_t)j * stride];
  if constexpr (RELU) s = s > 0.f ? s : 0.f;
  out[i] = f2bf(s);
}

// ================= 128^2 MFMA GEMM (m97 structure) =================
// EPI: 3 sigmoid*aux bf16, 6 split-K x8 f32 partial, 7 split-K x2 f32 partial
template <int EPI>
__launch_bounds__(256, 2)
__global__ void gemm_bt(const ushort_t* __restrict__ A, const ushort_t* __restrict__ BT,
                        void* __restrict__ C, const float* __restrict__ bias,
                        const ushort_t* __restrict__ aux, int M, int N, int K) {
  __shared__ ushort_t ldsA[128 * 32];
  __shared__ ushort_t ldsB[128 * 32];
  const int t = threadIdx.x;
  const int wave = t >> 6, lane = t & 63;
  const int bm = blockIdx.x, bn = blockIdx.y;
  const int wr = wave >> 1, wc = wave & 1;
  const int lrow = lane & 15, lk = lane >> 4;

  f32x4 acc[4][4] = {};

  const size_t arow0 = (size_t)bm * 128;
  const size_t brow0 = (size_t)bn * 128;

  int kb = 0, ke = K;
  if constexpr (EPI == 6) { int ks = K >> 3; kb = blockIdx.z * ks; ke = kb + ks; }
  if constexpr (EPI == 7) { int ks = K >> 1; kb = blockIdx.z * ks; ke = kb + ks; }

  for (int k0 = kb; k0 < ke; k0 += 32) {
    if (k0 != kb) __syncthreads();
    #pragma unroll
    for (int h = 0; h < 2; ++h) {
      int q = t + h * 256;
      int row = q >> 2, slot = q & 3;
      int kc = slot ^ ((row >> 1) & 3);
      const ushort_t* ga = A + (arow0 + row) * K + k0 + kc * 8;
      gload_lds16(ga, &ldsA[(wave * 64 + h * 256) * 8]);
      const ushort_t* gb = BT + (brow0 + row) * K + k0 + kc * 8;
      gload_lds16(gb, &ldsB[(wave * 64 + h * 256) * 8]);
    }
    __syncthreads();

    short8 af[4], bfr[4];
    #pragma unroll
    for (int m = 0; m < 4; ++m) {
      int row = wr * 64 + m * 16 + lrow;
      int slot = lk ^ ((row >> 1) & 3);
      af[m] = *(const short8*)&ldsA[row * 32 + slot * 8];
      int rowb = wc * 64 + m * 16 + lrow;
      int slotb = lk ^ ((rowb >> 1) & 3);
      bfr[m] = *(const short8*)&ldsB[rowb * 32 + slotb * 8];
    }
    #pragma unroll
    for (int m = 0; m < 4; ++m)
      #pragma unroll
      for (int n = 0; n < 4; ++n)
        acc[m][n] = __builtin_amdgcn_mfma_f32_16x16x32_bf16(af[m], bfr[n], acc[m][n], 0, 0, 0);
  }

  const int rbase = bm * 128 + wr * 64;
  const int cbase = bn * 128 + wc * 64;
  #pragma unroll
  for (int m = 0; m < 4; ++m) {
    #pragma unroll
    for (int n = 0; n < 4; ++n) {
      int col = cbase + n * 16 + lrow;
      int row0 = rbase + m * 16 + lk * 4;
      #pragma unroll
      for (int j = 0; j < 4; ++j) {
        int r = row0 + j;
        float v = acc[m][n][j];
        size_t off = (size_t)r * N + col;
        if constexpr (EPI == 3) {
          float y = 1.f / (1.f + __expf(-v));
          ((ushort_t*)C)[off] = f2bf(bf2f(aux[off]) * y);
        } else {
          ((float*)C)[off + (size_t)blockIdx.z * ((size_t)M * N)] = v;
        }
      }
    }
  }
}

// ================= 256^2 8-phase MFMA GEMM, ONE barrier per phase =================
// Fixed shape: M=8192, N=2048, K=2048 (both call sites). BM=BN=256, BK=64,
// 512 thr = 8 waves (2M x 4N), per-wave 128x64 out.
// LDS 128KB: buf b at b*65536; A halves +0/+16384; B halves +32768/+49152.
// G4 swizzle: column chunk ^= (row&7)<<4 on staging source and ds_read
// (bank-conflict-free, measured 0 in R4/R7). R7's proven margin-2 one-barrier
// schedule, unchanged. This revision only precomputes per-thread staging
// addresses (srow/scb are t-invariant across calls; l=1 differs by exactly
// +64*KB global / +8192B LDS) and folds K/N as compile-time constants.
#define KB 4096            // K row bytes
#define NT 32              // K tiles

__device__ __forceinline__ short8 ldfrag(const char* regionBase, int R, int kk, int lk) {
  int r = R & 127, h = R >> 7;
  int col = (kk * 64 + lk * 16) ^ ((r & 7) << 4);
  return *(const short8*)(regionBase + h * 16384 + r * 128 + col);
}

template <int EPI>   // 1: +bias bf16 out; 4: +bias f32 out
__launch_bounds__(512, 2)
__global__ void gemm256(const ushort_t* __restrict__ A, const ushort_t* __restrict__ BT,
                        void* __restrict__ C, const float* __restrict__ bias) {
  __shared__ __align__(16) char L[131072];
  const int t = threadIdx.x;
  const int lane = t & 63, wave = t >> 6;
  const int wm = wave >> 2, wn = wave & 3;
  const int lrow = lane & 15, lk = lane >> 4;

  // bijective XCD swizzle (grid 256 = 8 XCD x 32)
  int d = blockIdx.x;
  int wg = (d & 7) * 32 + (d >> 3);
  const int bm = wg >> 3, bn = wg & 7;

  // per-thread staging constants
  const int srow = t >> 3;                                   // 0..63
  const int scb = ((t & 7) * 16) ^ ((srow & 7) << 4);
  const size_t rc0 = (size_t)srow * KB + scb;
  const int dst0 = (t & ~63) * 16;

  const char* aH0 = (const char*)A + (size_t)bm * 256 * KB;
  const char* aH1 = aH0 + (size_t)128 * KB;
  const char* bH0 = (const char*)BT + (size_t)bn * 256 * KB;
  const char* bH1 = bH0 + (size_t)128 * KB;

#define STG(srcHalf, k0b, ldsOff)                                         \
  do {                                                                    \
    gload_lds16((srcHalf) + (k0b) + rc0, L + (ldsOff) + dst0);            \
    gload_lds16((srcHalf) + (k0b) + rc0 + (size_t)64 * KB,                \
                L + (ldsOff) + dst0 + 8192);                              \
  } while (0)

  f32x4 acc[8][4] = {};

  // prologue: tile0 A+B -> buf0, B(1) -> buf1.B
  STG(aH0, 0, 0);
  STG(aH1, 0, 16384);
  STG(bH0, 0, 32768);
  STG(bH1, 0, 49152);
  STG(bH0, 128, 65536 + 32768);
  STG(bH1, 128, 65536 + 49152);
  asm volatile("s_waitcnt vmcnt(4)" ::: "memory");   // buf0 certified; B(1) in flight
  __builtin_amdgcn_s_barrier();

  short8 bfrag[4][2];
  short8 afrag[2][2];

  for (int T = 0; T < NT; T += 2) {
    int k1 = ((T + 1 < NT) ? T + 1 : NT - 1) * 128;
    int k2 = ((T + 2 < NT) ? T + 2 : NT - 1) * 128;
    int k3 = ((T + 3 < NT) ? T + 3 : NT - 1) * 128;
    #pragma unroll
    for (int ph = 0; ph < 8; ++ph) {
      const int cb = ph >> 2;          // compute buffer
      const int cp = ph & 3;           // sub-phase within K-tile
      const char* Ab = L + cb * 65536;
      const char* Bb = L + cb * 65536 + 32768;

      // ---- reads for THIS phase's MFMA ----
      if (cp == 0) {
        #pragma unroll
        for (int n = 0; n < 4; ++n)
          #pragma unroll
          for (int kk = 0; kk < 2; ++kk)
            bfrag[n][kk] = ldfrag(Bb, wn * 64 + n * 16 + lrow, kk, lk);
      }
      #pragma unroll
      for (int mi = 0; mi < 2; ++mi)
        #pragma unroll
        for (int kk = 0; kk < 2; ++kk)
          afrag[mi][kk] = ldfrag(Ab, wm * 128 + (cp * 2 + mi) * 16 + lrow, kk, lk);

      // ---- staging per margin-2 ledger + counted vmcnt (R7 schedule) ----
      if (ph == 1) {
        STG(aH0, k1, 65536);
        STG(aH1, k1, 65536 + 16384);
      } else if (ph == 2) {
        STG(bH0, k2, 32768);
      } else if (ph == 3) {
        STG(bH1, k2, 49152);
        asm volatile("s_waitcnt vmcnt(4)" ::: "memory");   // A(T+1),B(T+1) landed
      } else if (ph == 5) {
        STG(aH0, k2, 0);
      } else if (ph == 6) {
        STG(aH1, k2, 16384);
      } else if (ph == 7) {
        STG(bH0, k3, 65536 + 32768);
        STG(bH1, k3, 65536 + 49152);
        asm volatile("s_waitcnt vmcnt(4)" ::: "memory");   // A(T+2),B(T+2) landed
      }

      __builtin_amdgcn_s_barrier();
      asm volatile("s_waitcnt lgkmcnt(0)" ::: "memory");
      __builtin_amdgcn_sched_barrier(0);
      __builtin_amdgcn_s_setprio(1);
      #pragma unroll
      for (int mi = 0; mi < 2; ++mi)
        #pragma unroll
        for (int n = 0; n < 4; ++n)
          #pragma unroll
          for (int kk = 0; kk < 2; ++kk)
            acc[cp * 2 + mi][n] = __builtin_amdgcn_mfma_f32_16x16x32_bf16(
                afrag[mi][kk], bfrag[n][kk], acc[cp * 2 + mi][n], 0, 0, 0);
      __builtin_amdgcn_s_setprio(0);
      // no second barrier: margin-2 ledger makes it unnecessary
    }
  }

  const int rbase = bm * 256 + wm * 128;
  const int cbase = bn * 256 + wn * 64;
  #pragma unroll
  for (int mi = 0; mi < 8; ++mi) {
    #pragma unroll
    for (int n = 0; n < 4; ++n) {
      int col = cbase + n * 16 + lrow;
      int row0 = rbase + mi * 16 + lk * 4;
      float bcol = bias[col];
      #pragma unroll
      for (int j = 0; j < 4; ++j) {
        float v = acc[mi][n][j] + bcol;
        size_t off = (size_t)(row0 + j) * 2048 + col;
        if constexpr (EPI == 4) ((float*)C)[off] = v;
        else                    ((ushort_t*)C)[off] = f2bf(v);
      }
    }
  }
#undef STG
}

extern "C" void kernel_launch(void* const* d_in, const int* in_sizes, int n_in,
                              void* d_out, int out_size, void* d_ws, size_t ws_size,
                              hipStream_t stream) {
  const float* x     = (const float*)d_in[0];
  const float* W_in  = (const float*)d_in[1];
  const float* b_in  = (const float*)d_in[2];
  const float* W_out = (const float*)d_in[3];
  const float* b_out = (const float*)d_in[4];
  const float* fg    = (const float*)d_in[5];
  const float* W_fc1 = (const float*)d_in[6];
  const float* W_fc2 = (const float*)d_in[7];

  char* ws = (char*)d_ws;
  float*    c_buf  = (float*)(ws + 0);               // 8 KB
  float*    b1     = (float*)(ws + 8192);            // 8 KB
  ushort_t* WinBf  = (ushort_t*)(ws + 16384);        // 8 MB
  ushort_t* W1T    = (ushort_t*)(ws + 8404992);      // 8 MB
  ushort_t* WoutT  = (ushort_t*)(ws + 16793600);     // 8 MB
  ushort_t* Wfc1eT = (ushort_t*)(ws + 25182208);     // 512 KB
  ushort_t* Wfc2T  = (ushort_t*)(ws + 25706496);     // 512 KB
  ushort_t* x_bf   = (ushort_t*)(ws + 26230784);     // 32 MB (dead after ht GEMM)
  float*    fcp    = (float*)(ws + 26230784);        // 32 MB, aliases x_bf (step 6+)
  ushort_t* ht_bf  = (ushort_t*)(ws + 59785216);     // 32 MB
  float*    foldp  = (float*)(ws + 59785216);        // 32 MB fold partials, aliases
                                                     // ht_bf (dead before ht GEMM)
  ushort_t* a_bf   = (ushort_t*)(ws + 93339648);     // 2 MB
  ushort_t* GT     = (ushort_t*)(ws + 95436800);     // 8 MB (dead after fold GEMM)
  ushort_t* g_bf   = (ushort_t*)(ws + 95436800);     // 32 MB, aliases GT
  (void)ws_size; (void)in_sizes; (void)n_in; (void)out_size;

  // 1. all input-only prep (c, casts, transposes, fc1 fold) in one kernel
  k_prep_w<<<27904, 256, 0, stream>>>(fg, c_buf, W_in, WinBf, x, x_bf,
                                      W_out, WoutT, W_fc2, Wfc2T, W_fc1, Wfc1eT);
  // 2. c-dependent prep: b1 + GT
  k_prep_c<<<10240, 256, 0, stream>>>(b_in, c_buf, b1, (uint_t*)GT);
  // 3. W1T = GT @ WinBf^T  [2048 x 2048], split-K x2 -> f32 partials
  gemm_bt<7><<<dim3(16, 16, 2), 256, 0, stream>>>(GT, WinBf, foldp, nullptr, nullptr,
                                                  2048, 2048, 2048);
  // 4. W1T = bf16(sum partials)
  k_redN<0, 2><<<16384, 256, 0, stream>>>(foldp, W1T, 4194304);
  // 5. ht = x @ W1 + b1   [8192 x 2048] bf16   (256^2 one-barrier 8-phase)
  gemm256<1><<<256, 512, 0, stream>>>(x_bf, W1T, ht_bf, b1);
  // 6. fc1 split-K x8: partials = ht @ Wfc1e  [8][8192 x 128] f32
  gemm_bt<6><<<dim3(64, 1, 8), 256, 0, stream>>>(ht_bf, Wfc1eT, fcp, nullptr, nullptr,
                                                 8192, 128, 2048);
  // 7. a = relu(sum partials)                  [8192 x 128] bf16
  k_redN<1, 8><<<4096, 256, 0, stream>>>(fcp, a_bf, 1048576);
  // 8. g = ht * sigmoid(a @ Wfc2)             [8192 x 2048] bf16
  gemm_bt<3><<<dim3(64, 16), 256, 0, stream>>>(a_bf, Wfc2T, g_bf, nullptr, ht_bf,
                                               8192, 2048, 128);
  // 9. out = g @ W_out + b_out                [8192 x 2048] f32
  gemm256<4><<<256, 512, 0, stream>>>(g_bf, WoutT, (float*)d_out, b_out);
}